// Round 13
// baseline (184.674 us; speedup 1.0000x reference)
//
#include <hip/hip_runtime.h>
#include <math.h>

// Problem constants (fixed by the reference)
#define NB   256                 // graphs
#define NPG  256                 // nodes per graph
#define NN   (NB * NPG)          // 65536 nodes
#define NE   (NN * 16)           // 1048576 edges
#define EPG  (NE / NB)           // 4096 edges per graph
#define FD   128                 // F == H
#define NC   10
#define NSL  32                  // slices (1024 threads / 32 lanes-per-slice)
#define NEG_INF (-3.402823466e38f)

// Shared-memory layout for the fused per-graph block: ~163 KB <= 160 KiB.
struct SM {
    float hs[NPG][FD];          // 128 KB: x -> hW -> gated h (in place across levels)
    int   rp[NPG + 4];          // local CSR row pointers
    float nmloc[NPG];           // node mask
    float dvv[NPG];             // dinv
    float sw[NPG];              // score matvec result / MLP h1
    float sf[NPG];              // score conv result (by node id) / MLP h2
    float svv[NPG];             // sort staging / MLP logits buffer
    float th[NPG];              // tanh(score) for kept
    float zacc[2 * FD];         // readout accumulator across levels
    int   si[NPG];              // sort staging / CSR counts
    int   kept[NPG];            // kept flags / CSR scatter cursor
    int   anode[NPG];           // active list / CSR scan buffer
    float red_mx[16][FD];       // per-wave readout partials
    float red_sm[16][FD];
    unsigned char colb[EPG];    // edge src local ids (CSR-by-dst order), 4 KB
};

// Swizzled access to feature-quad q (16B) of row v: physical quad = q ^ (v&7).
// Banks repeat every 8 quads, so this de-aliases different rows accessed at
// the same feature offset by the two half-waves of a wave64.
__device__ __forceinline__ float4& hsq(SM& sm, int v, int q) {
    return *(float4*)&sm.hs[v][(q ^ (v & 7)) << 2];
}

// ---------------------------------------------------------------------------
// One pooling level, fully in-LDS. NACT = active node count (256/128/64).
// Thread layout: f4 = tid&31 (feature quad), s = tid>>5 (slice 0..31);
// slice s owns active indices i = c*32+s, c < NPS = NACT/32.
// ---------------------------------------------------------------------------
template <int NACT>
__device__ __forceinline__ void do_level(SM& sm,
                                         const float* __restrict__ Wmat,
                                         const float* __restrict__ bias,
                                         const float* __restrict__ Wp,
                                         const float* __restrict__ bpp,
                                         int tid) {
    constexpr int NPS = NACT / NSL;      // rows per slice
    constexpr int K   = NACT / 2;
    constexpr int TPN = 1024 / NACT;     // threads per node in score conv
    const int f4 = tid & 31;
    const int s  = tid >> 5;

    // ---- dinv: 4 threads per node (all 1024 threads active) ----
    // Independent of the GEMM below -> overlaps with it; published by the
    // barrier after the GEMM.
    {
        const int n = tid >> 2, sub = tid & 3;
        float part = 0.f;
        const float nmn = sm.nmloc[n];
        if (nmn > 0.f) {
            const int e1 = sm.rp[n + 1];
            for (int e = sm.rp[n] + sub; e < e1; e += 4)
                part += sm.nmloc[sm.colb[e]];
        }
        part += __shfl_xor(part, 1);
        part += __shfl_xor(part, 2);
        if (sub == 0)
            sm.dvv[n] = (nmn > 0.f) ? rsqrtf(1.f + part) : 0.f;
    }

    // ---- in-place GEMM on active rows: hs[v] <- hs[v] @ W ----
    // W block for kq+1 is prefetched (register double-buffer) before the
    // FMAs of kq, covering L2 latency. amdgpu_waves_per_eu(4,4) gives the
    // allocator 128 VGPRs (LDS caps us at 4 waves/EU anyway) -> no spill.
    // Row v is read and written only by the 32 lanes of the half-wave that
    // owns it (lockstep) -> no barrier needed around the in-place update.
    {
        int vr[NPS];
        float4 acc[NPS];
#pragma unroll
        for (int c = 0; c < NPS; ++c) {
            vr[c] = sm.anode[c * NSL + s];
            acc[c] = make_float4(0.f, 0.f, 0.f, 0.f);
        }
        const float* __restrict__ Wl = Wmat + 4 * f4;
        float4 w0 = *(const float4*)&Wl[0 * FD];
        float4 w1 = *(const float4*)&Wl[1 * FD];
        float4 w2 = *(const float4*)&Wl[2 * FD];
        float4 w3 = *(const float4*)&Wl[3 * FD];
        for (int kq = 0; kq < 32; ++kq) {
            float4 nw0, nw1, nw2, nw3;
            if (kq < 31) {
                const float* __restrict__ Wn = Wl + (4 * kq + 4) * FD;
                nw0 = *(const float4*)&Wn[0 * FD];
                nw1 = *(const float4*)&Wn[1 * FD];
                nw2 = *(const float4*)&Wn[2 * FD];
                nw3 = *(const float4*)&Wn[3 * FD];
            }
#pragma unroll
            for (int c = 0; c < NPS; ++c) {
                float4 hv = hsq(sm, vr[c], kq);
                acc[c].x += hv.x * w0.x + hv.y * w1.x + hv.z * w2.x + hv.w * w3.x;
                acc[c].y += hv.x * w0.y + hv.y * w1.y + hv.z * w2.y + hv.w * w3.y;
                acc[c].z += hv.x * w0.z + hv.y * w1.z + hv.z * w2.z + hv.w * w3.z;
                acc[c].w += hv.x * w0.w + hv.y * w1.w + hv.z * w2.w + hv.w * w3.w;
            }
            w0 = nw0; w1 = nw1; w2 = nw2; w3 = nw3;
        }
#pragma unroll
        for (int c = 0; c < NPS; ++c)
            hsq(sm, vr[c], f4) = acc[c];
    }
    __syncthreads();   // publishes GEMM rows + dvv

    // ---- conv + relu + fused score matvec (active nodes only) ----
    const float4 b4  = *(const float4*)&bias[4 * f4];
    const float4 wp4 = *(const float4*)&Wp[4 * f4];
    float4 hreg[NPS];
#pragma unroll
    for (int c = 0; c < NPS; ++c) {
        const int v = sm.anode[c * NSL + s];
        const float dv_ = sm.dvv[v], dv2 = dv_ * dv_;
        const float4 hv = hsq(sm, v, f4);
        float4 acc;
        acc.x = hv.x * dv2 + b4.x;
        acc.y = hv.y * dv2 + b4.y;
        acc.z = hv.z * dv2 + b4.z;
        acc.w = hv.w * dv2 + b4.w;
        const int e0 = sm.rp[v], e1 = sm.rp[v + 1];
        int e = e0;
        for (; e + 4 <= e1; e += 4) {
            int u0 = sm.colb[e],     u1 = sm.colb[e + 1];
            int u2 = sm.colb[e + 2], u3 = sm.colb[e + 3];
            float w0 = sm.dvv[u0] * dv_, w1 = sm.dvv[u1] * dv_;
            float w2 = sm.dvv[u2] * dv_, w3 = sm.dvv[u3] * dv_;
            float4 h0 = hsq(sm, u0, f4);
            float4 h1 = hsq(sm, u1, f4);
            float4 h2 = hsq(sm, u2, f4);
            float4 h3 = hsq(sm, u3, f4);
            acc.x += w0 * h0.x + w1 * h1.x + w2 * h2.x + w3 * h3.x;
            acc.y += w0 * h0.y + w1 * h1.y + w2 * h2.y + w3 * h3.y;
            acc.z += w0 * h0.z + w1 * h1.z + w2 * h2.z + w3 * h3.z;
            acc.w += w0 * h0.w + w1 * h1.w + w2 * h2.w + w3 * h3.w;
        }
        for (; e < e1; ++e) {
            int u = sm.colb[e];
            float w = sm.dvv[u] * dv_;
            float4 hu = hsq(sm, u, f4);
            acc.x += w * hu.x; acc.y += w * hu.y;
            acc.z += w * hu.z; acc.w += w * hu.w;
        }
        acc.x = fmaxf(acc.x, 0.f);
        acc.y = fmaxf(acc.y, 0.f);
        acc.z = fmaxf(acc.z, 0.f);
        acc.w = fmaxf(acc.w, 0.f);
        hreg[c] = acc;
        // score partial: dot(h[v], Wp) reduced across the 32 f4 lanes
        float p = acc.x * wp4.x + acc.y * wp4.y + acc.z * wp4.z + acc.w * wp4.w;
        p += __shfl_xor(p, 1);
        p += __shfl_xor(p, 2);
        p += __shfl_xor(p, 4);
        p += __shfl_xor(p, 8);
        p += __shfl_xor(p, 16);
        if (f4 == 0) sm.sw[v] = p;
    }
    __syncthreads();

    // ---- score conv: TPN threads per active node (all lanes busy) ----
    {
        const int i = tid / TPN, sub = tid % TPN;
        const int v = sm.anode[i];
        const float dv_ = sm.dvv[v];
        float part = 0.f;
        const int e1 = sm.rp[v + 1];
        for (int e = sm.rp[v] + sub; e < e1; e += TPN) {
            int u = sm.colb[e];
            part += sm.dvv[u] * sm.sw[u];
        }
#pragma unroll
        for (int o = 1; o < TPN; o <<= 1) part += __shfl_xor(part, o);
        if (sub == 0) {
            float acc = sm.sw[v] * dv_ * dv_ + bpp[0] + dv_ * part;
            sm.sf[v] = acc;        // by node id (for tanh later)
            sm.svv[i] = acc;       // by active index (for sort)
        }
    }
    __syncthreads();

    // ---- bitonic sort of NACT active elements, registers + shuffles ----
    // comparator: value desc, node-id asc  (= jax.lax.top_k semantics)
    float v_ = 0.f;
    int   id_ = 0;
    if (tid < NACT) { v_ = sm.svv[tid]; id_ = sm.anode[tid]; }
#pragma unroll
    for (int k = 2; k <= NACT; k <<= 1) {
#pragma unroll
        for (int j = k >> 1; j > 0; j >>= 1) {
            if (j < 64) {
                if (tid < NACT) {
                    float vp = __shfl_xor(v_, j);
                    int  idp = __shfl_xor(id_, j);
                    bool up    = ((tid & k) == 0);
                    bool lower = ((tid & j) == 0);
                    bool g = (v_ > vp) || (v_ == vp && id_ < idp);
                    if (g != (lower == up)) { v_ = vp; id_ = idp; }
                }
            } else {
                if (tid < NACT) { sm.svv[tid] = v_; sm.si[tid] = id_; }
                __syncthreads();
                if (tid < NACT) {
                    int p = tid ^ j;
                    float vp = sm.svv[p];
                    int  idp = sm.si[p];
                    bool up    = ((tid & k) == 0);
                    bool lower = ((tid & j) == 0);
                    bool g = (v_ > vp) || (v_ == vp && id_ < idp);
                    if (g != (lower == up)) { v_ = vp; id_ = idp; }
                }
                __syncthreads();
            }
        }
    }
    if (tid < NPG) sm.kept[tid] = 0;
    __syncthreads();
    if (tid < K) {
        sm.kept[id_] = 1;
        sm.th[id_] = tanhf(sm.sf[id_]);
    }
    __syncthreads();

    // ---- tanh-gate: write kept rows back into hs; readout partials ----
    float4 mx4 = make_float4(NEG_INF, NEG_INF, NEG_INF, NEG_INF);
    float4 sm4 = make_float4(0.f, 0.f, 0.f, 0.f);
#pragma unroll
    for (int c = 0; c < NPS; ++c) {
        const int v = sm.anode[c * NSL + s];
        if (sm.kept[v]) {
            const float tg = sm.th[v];
            float4 val;
            val.x = hreg[c].x * tg;
            val.y = hreg[c].y * tg;
            val.z = hreg[c].z * tg;
            val.w = hreg[c].w * tg;
            hsq(sm, v, f4) = val;
            mx4.x = fmaxf(mx4.x, val.x); sm4.x += val.x;
            mx4.y = fmaxf(mx4.y, val.y); sm4.y += val.y;
            mx4.z = fmaxf(mx4.z, val.z); sm4.z += val.z;
            mx4.w = fmaxf(mx4.w, val.w); sm4.w += val.w;
        }
    }
    mx4.x = fmaxf(mx4.x, __shfl_xor(mx4.x, 32)); sm4.x += __shfl_xor(sm4.x, 32);
    mx4.y = fmaxf(mx4.y, __shfl_xor(mx4.y, 32)); sm4.y += __shfl_xor(sm4.y, 32);
    mx4.z = fmaxf(mx4.z, __shfl_xor(mx4.z, 32)); sm4.z += __shfl_xor(sm4.z, 32);
    mx4.w = fmaxf(mx4.w, __shfl_xor(mx4.w, 32)); sm4.w += __shfl_xor(sm4.w, 32);
    const int wv = tid >> 6;
    if ((tid & 63) < 32) {
        *(float4*)&sm.red_mx[wv][4 * f4] = mx4;
        *(float4*)&sm.red_sm[wv][4 * f4] = sm4;
    }
    __syncthreads();   // all threads done with gate loop + red writes
    if (tid < FD) {
        float mx = NEG_INF, smv = 0.f;
#pragma unroll
        for (int i = 0; i < 16; ++i) {
            mx = fmaxf(mx, sm.red_mx[i][tid]);
            smv += sm.red_sm[i][tid];
        }
        sm.zacc[tid] += mx;
        sm.zacc[FD + tid] += smv / (float)K;
    }
    // ---- update active set for next level ----
    if (tid < K) sm.anode[tid] = id_;
    if (tid < NPG) sm.nmloc[tid] = (float)sm.kept[tid];
    __syncthreads();
}

// ---------------------------------------------------------------------------
// Fully-fused kernel: one 1024-thread block per graph does CSR build, all
// 3 GCN+pool levels, readout, and the final MLP + log_softmax.
// amdgpu_waves_per_eu(4,4): LDS (159 KB) caps this kernel at 1 block/CU
// = 4 waves/EU, so pin the register budget to 512/4 = 128 VGPRs/wave.
// ---------------------------------------------------------------------------
__global__ __launch_bounds__(1024)
__attribute__((amdgpu_waves_per_eu(4, 4)))
void k_mega(const float* __restrict__ x, const int* __restrict__ ei,
            const float* __restrict__ W1, const float* __restrict__ b1,
            const float* __restrict__ Wp1, const float* __restrict__ bp1,
            const float* __restrict__ W2, const float* __restrict__ b2,
            const float* __restrict__ Wp2, const float* __restrict__ bp2,
            const float* __restrict__ W3, const float* __restrict__ b3,
            const float* __restrict__ Wp3, const float* __restrict__ bp3,
            const float* __restrict__ Wl1, const float* __restrict__ bl1,
            const float* __restrict__ Wl2, const float* __restrict__ bl2,
            const float* __restrict__ Wl3, const float* __restrict__ bl3,
            float* __restrict__ out) {
    __shared__ SM sm;
    const int g = blockIdx.x, tid = threadIdx.x;
    const int gbase = g * NPG, ebase = g * EPG;
    const int* __restrict__ srcA = ei;
    const int* __restrict__ dstA = ei + NE;

    // ---- read this block's edges once (coalesced) ----
    int myd[4], mys[4];
#pragma unroll
    for (int i = 0; i < 4; ++i) {
        int e = ebase + tid + i * 1024;
        myd[i] = dstA[e] - gbase;
        mys[i] = srcA[e] - gbase;
    }

    // ---- CSR-by-dst build (si = counts, anode = scan, kept = cursor) ----
    if (tid < NPG) sm.si[tid] = 0;
    __syncthreads();
#pragma unroll
    for (int i = 0; i < 4; ++i) atomicAdd(&sm.si[myd[i]], 1);
    __syncthreads();
    if (tid < NPG) sm.anode[tid] = sm.si[tid];
    __syncthreads();
    for (int o = 1; o < NPG; o <<= 1) {
        int add = 0;
        if (tid < NPG && tid >= o) add = sm.anode[tid - o];
        __syncthreads();
        if (tid < NPG) sm.anode[tid] += add;
        __syncthreads();
    }
    if (tid < NPG) {
        int excl = sm.anode[tid] - sm.si[tid];
        sm.rp[tid] = excl;
        sm.kept[tid] = excl;
        if (tid == 0) sm.rp[NPG] = EPG;
    }
    __syncthreads();
#pragma unroll
    for (int i = 0; i < 4; ++i) {
        int p = atomicAdd(&sm.kept[myd[i]], 1);
        sm.colb[p] = (unsigned char)mys[i];      // LOCAL src id as byte
    }

    // ---- stage x -> LDS (swizzled); init active set + readout acc ----
    {
        const int r0 = tid >> 5, f4 = tid & 31;
        for (int r = r0; r < NPG; r += NSL)
            hsq(sm, r, f4) =
                *(const float4*)&x[((size_t)(gbase + r)) * FD + 4 * f4];
    }
    if (tid < NPG) { sm.anode[tid] = tid; sm.nmloc[tid] = 1.f; }
    if (tid < 2 * FD) sm.zacc[tid] = 0.f;
    __syncthreads();   // colb + hs + state visible block-wide

    do_level<256>(sm, W1, b1, Wp1, bp1, tid);
    do_level<128>(sm, W2, b2, Wp2, bp2, tid);
    do_level<64>(sm, W3, b3, Wp3, bp3, tid);

    // ---- final MLP + log_softmax (reuse sw/sf/svv as h1/h2/logits) ----
    if (tid < 128) {
        float a = bl1[tid];
#pragma unroll 8
        for (int k = 0; k < 256; ++k) a += sm.zacc[k] * Wl1[k * 128 + tid];
        sm.sw[tid] = fmaxf(a, 0.f);
    }
    __syncthreads();
    if (tid < 64) {
        float a = bl2[tid];
#pragma unroll 8
        for (int k = 0; k < 128; ++k) a += sm.sw[k] * Wl2[k * 64 + tid];
        sm.sf[tid] = fmaxf(a, 0.f);
    }
    __syncthreads();
    if (tid < NC) {
        float a = bl3[tid];
#pragma unroll
        for (int k = 0; k < 64; ++k) a += sm.sf[k] * Wl3[k * NC + tid];
        sm.svv[tid] = a;
    }
    __syncthreads();
    if (tid == 0) {
        float m = sm.svv[0];
        for (int c = 1; c < NC; ++c) m = fmaxf(m, sm.svv[c]);
        float se = 0.f;
        for (int c = 0; c < NC; ++c) se += expf(sm.svv[c] - m);
        float lse = m + logf(se);
        for (int c = 0; c < NC; ++c) out[g * NC + c] = sm.svv[c] - lse;
    }
}

// ---------------------------------------------------------------------------
extern "C" void kernel_launch(void* const* d_in, const int* in_sizes, int n_in,
                              void* d_out, int out_size, void* d_ws, size_t ws_size,
                              hipStream_t stream) {
    const float* x   = (const float*)d_in[0];
    const int*   ei  = (const int*)d_in[1];
    const float* W1  = (const float*)d_in[3];
    const float* b1  = (const float*)d_in[4];
    const float* Wp1 = (const float*)d_in[5];
    const float* bp1 = (const float*)d_in[6];
    const float* W2  = (const float*)d_in[7];
    const float* b2  = (const float*)d_in[8];
    const float* Wp2 = (const float*)d_in[9];
    const float* bp2 = (const float*)d_in[10];
    const float* W3  = (const float*)d_in[11];
    const float* b3  = (const float*)d_in[12];
    const float* Wp3 = (const float*)d_in[13];
    const float* bp3 = (const float*)d_in[14];
    const float* Wl1 = (const float*)d_in[15];
    const float* bl1 = (const float*)d_in[16];
    const float* Wl2 = (const float*)d_in[17];
    const float* bl2 = (const float*)d_in[18];
    const float* Wl3 = (const float*)d_in[19];
    const float* bl3 = (const float*)d_in[20];
    float* out = (float*)d_out;

    k_mega<<<NB, 1024, 0, stream>>>(x, ei,
                                    W1, b1, Wp1, bp1,
                                    W2, b2, Wp2, bp2,
                                    W3, b3, Wp3, bp3,
                                    Wl1, bl1, Wl2, bl2, Wl3, bl3, out);
}

// Round 14
// 129.888 us; speedup vs baseline: 1.4218x; 1.4218x over previous
//
#include <hip/hip_runtime.h>
#include <math.h>

// Problem constants (fixed by the reference)
#define NB   256                 // graphs
#define NPG  256                 // nodes per graph
#define NN   (NB * NPG)          // 65536 nodes
#define NE   (NN * 16)           // 1048576 edges
#define EPG  (NE / NB)           // 4096 edges per graph
#define FD   128                 // F == H
#define NC   10
#define NSL  32                  // slices (1024 threads / 32 lanes-per-slice)
#define NEG_INF (-3.402823466e38f)

// Shared-memory layout for the fused per-graph block: ~163 KB <= 160 KiB.
struct SM {
    float hs[NPG][FD];          // 128 KB: x -> hW -> gated h (in place across levels)
    int   rp[NPG + 4];          // local CSR row pointers
    float nmloc[NPG];           // node mask
    float dvv[NPG];             // dinv
    float sw[NPG];              // score matvec result / MLP h1
    float sf[NPG];              // score conv result (by node id) / MLP h2
    float svv[NPG];             // sort staging / MLP logits buffer
    float th[NPG];              // tanh(score) for kept
    float zacc[2 * FD];         // readout accumulator across levels
    int   si[NPG];              // sort staging / CSR counts
    int   kept[NPG];            // kept flags / CSR scatter cursor
    int   anode[NPG];           // active list / CSR scan buffer
    float red_mx[16][FD];       // per-wave readout partials
    float red_sm[16][FD];
    unsigned char colb[EPG];    // edge src local ids (CSR-by-dst order), 4 KB
};

// Swizzled access to feature-quad q (16B) of row v: physical quad = q ^ (v&7).
// Banks repeat every 8 quads, so this de-aliases different rows accessed at
// the same feature offset by the two half-waves of a wave64.
__device__ __forceinline__ float4& hsq(SM& sm, int v, int q) {
    return *(float4*)&sm.hs[v][(q ^ (v & 7)) << 2];
}

// ---------------------------------------------------------------------------
// One pooling level, fully in-LDS. NACT = active node count (256/128/64).
// Thread layout: f4 = tid&31 (feature quad), s = tid>>5 (slice 0..31);
// slice s owns active indices i = c*32+s, c < NPS = NACT/32.
// NOTE: 1024-thread blocks are budgeted 64 VGPRs/lane by this toolchain
// (verified rounds 11-13: attempts to raise it spill to scratch). Keep all
// per-thread state small; no register pipelining.
// ---------------------------------------------------------------------------
template <int NACT>
__device__ __forceinline__ void do_level(SM& sm,
                                         const float* __restrict__ Wmat,
                                         const float* __restrict__ bias,
                                         const float* __restrict__ Wp,
                                         const float* __restrict__ bpp,
                                         int tid) {
    constexpr int NPS = NACT / NSL;      // rows per slice
    constexpr int K   = NACT / 2;
    constexpr int TPN = 1024 / NACT;     // threads per node in score conv
    const int f4 = tid & 31;
    const int s  = tid >> 5;

    // ---- dinv: 4 threads per node (all 1024 threads active) ----
    // Independent of the GEMM below -> overlaps with it; published by the
    // barrier after the GEMM.
    {
        const int n = tid >> 2, sub = tid & 3;
        float part = 0.f;
        const float nmn = sm.nmloc[n];
        if (nmn > 0.f) {
            const int e1 = sm.rp[n + 1];
            for (int e = sm.rp[n] + sub; e < e1; e += 4)
                part += sm.nmloc[sm.colb[e]];
        }
        part += __shfl_xor(part, 1);
        part += __shfl_xor(part, 2);
        if (sub == 0)
            sm.dvv[n] = (nmn > 0.f) ? rsqrtf(1.f + part) : 0.f;
    }

    // ---- in-place GEMM on active rows: hs[v] <- hs[v] @ W ----
    // Row v is read and written only by the 32 lanes of the half-wave that
    // owns it (lockstep) -> no barrier needed around the in-place update.
    {
        int vr[NPS];
        float4 acc[NPS];
#pragma unroll
        for (int c = 0; c < NPS; ++c) {
            vr[c] = sm.anode[c * NSL + s];
            acc[c] = make_float4(0.f, 0.f, 0.f, 0.f);
        }
#pragma unroll 2
        for (int kq = 0; kq < 32; ++kq) {
            const int k0 = kq << 2;
            float4 w0 = *(const float4*)&Wmat[(k0 + 0) * FD + 4 * f4];
            float4 w1 = *(const float4*)&Wmat[(k0 + 1) * FD + 4 * f4];
            float4 w2 = *(const float4*)&Wmat[(k0 + 2) * FD + 4 * f4];
            float4 w3 = *(const float4*)&Wmat[(k0 + 3) * FD + 4 * f4];
#pragma unroll
            for (int c = 0; c < NPS; ++c) {
                float4 hv = hsq(sm, vr[c], kq);
                acc[c].x += hv.x * w0.x + hv.y * w1.x + hv.z * w2.x + hv.w * w3.x;
                acc[c].y += hv.x * w0.y + hv.y * w1.y + hv.z * w2.y + hv.w * w3.y;
                acc[c].z += hv.x * w0.z + hv.y * w1.z + hv.z * w2.z + hv.w * w3.z;
                acc[c].w += hv.x * w0.w + hv.y * w1.w + hv.z * w2.w + hv.w * w3.w;
            }
        }
#pragma unroll
        for (int c = 0; c < NPS; ++c)
            hsq(sm, vr[c], f4) = acc[c];
    }
    __syncthreads();   // publishes GEMM rows + dvv

    // ---- conv + relu + fused score matvec (active nodes only) ----
    // colb read 4-at-a-time via aligned u32 (1 LDS instr for 4 edge ids).
    const float4 b4  = *(const float4*)&bias[4 * f4];
    const float4 wp4 = *(const float4*)&Wp[4 * f4];
    float4 hreg[NPS];
#pragma unroll
    for (int c = 0; c < NPS; ++c) {
        const int v = sm.anode[c * NSL + s];
        const float dv_ = sm.dvv[v], dv2 = dv_ * dv_;
        const float4 hv = hsq(sm, v, f4);
        float4 acc;
        acc.x = hv.x * dv2 + b4.x;
        acc.y = hv.y * dv2 + b4.y;
        acc.z = hv.z * dv2 + b4.z;
        acc.w = hv.w * dv2 + b4.w;
        const int e0 = sm.rp[v], e1 = sm.rp[v + 1];
        int e = e0;
        int ea = (e0 + 3) & ~3;                 // align head to 4
        if (ea > e1) ea = e1;
        for (; e < ea; ++e) {
            int u = sm.colb[e];
            float w = sm.dvv[u] * dv_;
            float4 hu = hsq(sm, u, f4);
            acc.x += w * hu.x; acc.y += w * hu.y;
            acc.z += w * hu.z; acc.w += w * hu.w;
        }
        for (; e + 4 <= e1; e += 4) {
            unsigned pk = *(const unsigned*)&sm.colb[e];
            int u0 = pk & 255, u1 = (pk >> 8) & 255;
            int u2 = (pk >> 16) & 255, u3 = pk >> 24;
            float w0 = sm.dvv[u0] * dv_, w1 = sm.dvv[u1] * dv_;
            float w2 = sm.dvv[u2] * dv_, w3 = sm.dvv[u3] * dv_;
            float4 h0 = hsq(sm, u0, f4);
            float4 h1 = hsq(sm, u1, f4);
            float4 h2 = hsq(sm, u2, f4);
            float4 h3 = hsq(sm, u3, f4);
            acc.x += w0 * h0.x + w1 * h1.x + w2 * h2.x + w3 * h3.x;
            acc.y += w0 * h0.y + w1 * h1.y + w2 * h2.y + w3 * h3.y;
            acc.z += w0 * h0.z + w1 * h1.z + w2 * h2.z + w3 * h3.z;
            acc.w += w0 * h0.w + w1 * h1.w + w2 * h2.w + w3 * h3.w;
        }
        for (; e < e1; ++e) {
            int u = sm.colb[e];
            float w = sm.dvv[u] * dv_;
            float4 hu = hsq(sm, u, f4);
            acc.x += w * hu.x; acc.y += w * hu.y;
            acc.z += w * hu.z; acc.w += w * hu.w;
        }
        acc.x = fmaxf(acc.x, 0.f);
        acc.y = fmaxf(acc.y, 0.f);
        acc.z = fmaxf(acc.z, 0.f);
        acc.w = fmaxf(acc.w, 0.f);
        hreg[c] = acc;
        // score partial: dot(h[v], Wp) reduced across the 32 f4 lanes
        float p = acc.x * wp4.x + acc.y * wp4.y + acc.z * wp4.z + acc.w * wp4.w;
        p += __shfl_xor(p, 1);
        p += __shfl_xor(p, 2);
        p += __shfl_xor(p, 4);
        p += __shfl_xor(p, 8);
        p += __shfl_xor(p, 16);
        if (f4 == 0) sm.sw[v] = p;
    }
    __syncthreads();

    // ---- score conv: TPN threads per active node (all lanes busy) ----
    {
        const int i = tid / TPN, sub = tid % TPN;
        const int v = sm.anode[i];
        const float dv_ = sm.dvv[v];
        float part = 0.f;
        const int e1 = sm.rp[v + 1];
        for (int e = sm.rp[v] + sub; e < e1; e += TPN) {
            int u = sm.colb[e];
            part += sm.dvv[u] * sm.sw[u];
        }
#pragma unroll
        for (int o = 1; o < TPN; o <<= 1) part += __shfl_xor(part, o);
        if (sub == 0) {
            float acc = sm.sw[v] * dv_ * dv_ + bpp[0] + dv_ * part;
            sm.sf[v] = acc;        // by node id (for tanh later)
            sm.svv[i] = acc;       // by active index (for sort)
        }
    }
    __syncthreads();

    // ---- bitonic sort of NACT active elements, registers + shuffles ----
    // comparator: value desc, node-id asc  (= jax.lax.top_k semantics)
    float v_ = 0.f;
    int   id_ = 0;
    if (tid < NACT) { v_ = sm.svv[tid]; id_ = sm.anode[tid]; }
#pragma unroll
    for (int k = 2; k <= NACT; k <<= 1) {
#pragma unroll
        for (int j = k >> 1; j > 0; j >>= 1) {
            if (j < 64) {
                if (tid < NACT) {
                    float vp = __shfl_xor(v_, j);
                    int  idp = __shfl_xor(id_, j);
                    bool up    = ((tid & k) == 0);
                    bool lower = ((tid & j) == 0);
                    bool g = (v_ > vp) || (v_ == vp && id_ < idp);
                    if (g != (lower == up)) { v_ = vp; id_ = idp; }
                }
            } else {
                if (tid < NACT) { sm.svv[tid] = v_; sm.si[tid] = id_; }
                __syncthreads();
                if (tid < NACT) {
                    int p = tid ^ j;
                    float vp = sm.svv[p];
                    int  idp = sm.si[p];
                    bool up    = ((tid & k) == 0);
                    bool lower = ((tid & j) == 0);
                    bool g = (v_ > vp) || (v_ == vp && id_ < idp);
                    if (g != (lower == up)) { v_ = vp; id_ = idp; }
                }
                __syncthreads();
            }
        }
    }
    if (tid < NPG) sm.kept[tid] = 0;
    __syncthreads();
    if (tid < K) {
        sm.kept[id_] = 1;
        sm.th[id_] = tanhf(sm.sf[id_]);
    }
    __syncthreads();

    // ---- tanh-gate: write kept rows back into hs; readout partials ----
    float4 mx4 = make_float4(NEG_INF, NEG_INF, NEG_INF, NEG_INF);
    float4 sm4 = make_float4(0.f, 0.f, 0.f, 0.f);
#pragma unroll
    for (int c = 0; c < NPS; ++c) {
        const int v = sm.anode[c * NSL + s];
        if (sm.kept[v]) {
            const float tg = sm.th[v];
            float4 val;
            val.x = hreg[c].x * tg;
            val.y = hreg[c].y * tg;
            val.z = hreg[c].z * tg;
            val.w = hreg[c].w * tg;
            hsq(sm, v, f4) = val;
            mx4.x = fmaxf(mx4.x, val.x); sm4.x += val.x;
            mx4.y = fmaxf(mx4.y, val.y); sm4.y += val.y;
            mx4.z = fmaxf(mx4.z, val.z); sm4.z += val.z;
            mx4.w = fmaxf(mx4.w, val.w); sm4.w += val.w;
        }
    }
    mx4.x = fmaxf(mx4.x, __shfl_xor(mx4.x, 32)); sm4.x += __shfl_xor(sm4.x, 32);
    mx4.y = fmaxf(mx4.y, __shfl_xor(mx4.y, 32)); sm4.y += __shfl_xor(sm4.y, 32);
    mx4.z = fmaxf(mx4.z, __shfl_xor(mx4.z, 32)); sm4.z += __shfl_xor(sm4.z, 32);
    mx4.w = fmaxf(mx4.w, __shfl_xor(mx4.w, 32)); sm4.w += __shfl_xor(sm4.w, 32);
    const int wv = tid >> 6;
    if ((tid & 63) < 32) {
        *(float4*)&sm.red_mx[wv][4 * f4] = mx4;
        *(float4*)&sm.red_sm[wv][4 * f4] = sm4;
    }
    __syncthreads();   // all threads done with gate loop + red writes
    if (tid < FD) {
        float mx = NEG_INF, smv = 0.f;
#pragma unroll
        for (int i = 0; i < 16; ++i) {
            mx = fmaxf(mx, sm.red_mx[i][tid]);
            smv += sm.red_sm[i][tid];
        }
        sm.zacc[tid] += mx;
        sm.zacc[FD + tid] += smv / (float)K;
    }
    // ---- update active set for next level ----
    if (tid < K) sm.anode[tid] = id_;
    if (tid < NPG) sm.nmloc[tid] = (float)sm.kept[tid];
    __syncthreads();
}

// ---------------------------------------------------------------------------
// Fully-fused kernel: one 1024-thread block per graph does CSR build, all
// 3 GCN+pool levels, readout, and the final MLP + log_softmax.
// ---------------------------------------------------------------------------
__global__ __launch_bounds__(1024)
void k_mega(const float* __restrict__ x, const int* __restrict__ ei,
            const float* __restrict__ W1, const float* __restrict__ b1,
            const float* __restrict__ Wp1, const float* __restrict__ bp1,
            const float* __restrict__ W2, const float* __restrict__ b2,
            const float* __restrict__ Wp2, const float* __restrict__ bp2,
            const float* __restrict__ W3, const float* __restrict__ b3,
            const float* __restrict__ Wp3, const float* __restrict__ bp3,
            const float* __restrict__ Wl1, const float* __restrict__ bl1,
            const float* __restrict__ Wl2, const float* __restrict__ bl2,
            const float* __restrict__ Wl3, const float* __restrict__ bl3,
            float* __restrict__ out) {
    __shared__ SM sm;
    const int g = blockIdx.x, tid = threadIdx.x;
    const int gbase = g * NPG, ebase = g * EPG;
    const int* __restrict__ srcA = ei;
    const int* __restrict__ dstA = ei + NE;

    // ---- read this block's edges once (coalesced) ----
    int myd[4], mys[4];
#pragma unroll
    for (int i = 0; i < 4; ++i) {
        int e = ebase + tid + i * 1024;
        myd[i] = dstA[e] - gbase;
        mys[i] = srcA[e] - gbase;
    }

    // ---- CSR-by-dst build (si = counts, anode = scan, kept = cursor) ----
    if (tid < NPG) sm.si[tid] = 0;
    __syncthreads();
#pragma unroll
    for (int i = 0; i < 4; ++i) atomicAdd(&sm.si[myd[i]], 1);
    __syncthreads();
    if (tid < NPG) sm.anode[tid] = sm.si[tid];
    __syncthreads();
    for (int o = 1; o < NPG; o <<= 1) {
        int add = 0;
        if (tid < NPG && tid >= o) add = sm.anode[tid - o];
        __syncthreads();
        if (tid < NPG) sm.anode[tid] += add;
        __syncthreads();
    }
    if (tid < NPG) {
        int excl = sm.anode[tid] - sm.si[tid];
        sm.rp[tid] = excl;
        sm.kept[tid] = excl;
        if (tid == 0) sm.rp[NPG] = EPG;
    }
    __syncthreads();
#pragma unroll
    for (int i = 0; i < 4; ++i) {
        int p = atomicAdd(&sm.kept[myd[i]], 1);
        sm.colb[p] = (unsigned char)mys[i];      // LOCAL src id as byte
    }

    // ---- stage x -> LDS (swizzled); init active set + readout acc ----
    {
        const int r0 = tid >> 5, f4 = tid & 31;
        for (int r = r0; r < NPG; r += NSL)
            hsq(sm, r, f4) =
                *(const float4*)&x[((size_t)(gbase + r)) * FD + 4 * f4];
    }
    if (tid < NPG) { sm.anode[tid] = tid; sm.nmloc[tid] = 1.f; }
    if (tid < 2 * FD) sm.zacc[tid] = 0.f;
    __syncthreads();   // colb + hs + state visible block-wide

    do_level<256>(sm, W1, b1, Wp1, bp1, tid);
    do_level<128>(sm, W2, b2, Wp2, bp2, tid);
    do_level<64>(sm, W3, b3, Wp3, bp3, tid);

    // ---- final MLP + log_softmax (reuse sw/sf/svv as h1/h2/logits) ----
    if (tid < 128) {
        float a = bl1[tid];
#pragma unroll 8
        for (int k = 0; k < 256; ++k) a += sm.zacc[k] * Wl1[k * 128 + tid];
        sm.sw[tid] = fmaxf(a, 0.f);
    }
    __syncthreads();
    if (tid < 64) {
        float a = bl2[tid];
#pragma unroll 8
        for (int k = 0; k < 128; ++k) a += sm.sw[k] * Wl2[k * 64 + tid];
        sm.sf[tid] = fmaxf(a, 0.f);
    }
    __syncthreads();
    if (tid < NC) {
        float a = bl3[tid];
#pragma unroll
        for (int k = 0; k < 64; ++k) a += sm.sf[k] * Wl3[k * NC + tid];
        sm.svv[tid] = a;
    }
    __syncthreads();
    if (tid == 0) {
        float m = sm.svv[0];
        for (int c = 1; c < NC; ++c) m = fmaxf(m, sm.svv[c]);
        float se = 0.f;
        for (int c = 0; c < NC; ++c) se += expf(sm.svv[c] - m);
        float lse = m + logf(se);
        for (int c = 0; c < NC; ++c) out[g * NC + c] = sm.svv[c] - lse;
    }
}

// ---------------------------------------------------------------------------
extern "C" void kernel_launch(void* const* d_in, const int* in_sizes, int n_in,
                              void* d_out, int out_size, void* d_ws, size_t ws_size,
                              hipStream_t stream) {
    const float* x   = (const float*)d_in[0];
    const int*   ei  = (const int*)d_in[1];
    const float* W1  = (const float*)d_in[3];
    const float* b1  = (const float*)d_in[4];
    const float* Wp1 = (const float*)d_in[5];
    const float* bp1 = (const float*)d_in[6];
    const float* W2  = (const float*)d_in[7];
    const float* b2  = (const float*)d_in[8];
    const float* Wp2 = (const float*)d_in[9];
    const float* bp2 = (const float*)d_in[10];
    const float* W3  = (const float*)d_in[11];
    const float* b3  = (const float*)d_in[12];
    const float* Wp3 = (const float*)d_in[13];
    const float* bp3 = (const float*)d_in[14];
    const float* Wl1 = (const float*)d_in[15];
    const float* bl1 = (const float*)d_in[16];
    const float* Wl2 = (const float*)d_in[17];
    const float* bl2 = (const float*)d_in[18];
    const float* Wl3 = (const float*)d_in[19];
    const float* bl3 = (const float*)d_in[20];
    float* out = (float*)d_out;

    k_mega<<<NB, 1024, 0, stream>>>(x, ei,
                                    W1, b1, Wp1, bp1,
                                    W2, b2, Wp2, bp2,
                                    W3, b3, Wp3, bp3,
                                    Wl1, bl1, Wl2, bl2, Wl3, bl3, out);
}